// Round 5
// baseline (116.005 us; speedup 1.0000x reference)
//
#include <hip/hip_runtime.h>
#include <hip/hip_bf16.h>
#include <cstdint>

#define BB 512
#define NN 512
#define FF 512
#define DD 256
#define KTOP 10
#define BN (BB*NN)          // 262144 rows
#define BM 16               // rows per tile (32 KB f32)
#define NTILES (BN/BM)      // 16384
#define GRID 256            // 1 block per CU
#define TPB (NTILES/GRID)   // 64 tiles per block, contiguous

typedef __attribute__((ext_vector_type(8))) short bf16x8;
typedef __attribute__((ext_vector_type(4))) short s16x4;
typedef __attribute__((ext_vector_type(4))) float f32x4;

__device__ __forceinline__ ushort f2bf(float x){
  union { __hip_bfloat16 h; ushort u; } cv;
  cv.h = __float2bfloat16(x);        // HW RNE; pairs fuse to v_cvt_pk_bf16_f32
  return cv.u;
}

__device__ __forceinline__ bf16x8 cvt8(f32x4 a, f32x4 b){
  bf16x8 r;
  r[0]=(short)f2bf(a[0]); r[1]=(short)f2bf(a[1]); r[2]=(short)f2bf(a[2]); r[3]=(short)f2bf(a[3]);
  r[4]=(short)f2bf(b[0]); r[5]=(short)f2bf(b[1]); r[6]=(short)f2bf(b[2]); r[7]=(short)f2bf(b[3]);
  return r;
}

// global f32 -> LDS, 16B/lane, linear LDS dest (wave-uniform base + lane*16)
#define GL2LDS(GSRC, LDST)                                                          \
  __builtin_amdgcn_global_load_lds(                                                 \
      (const __attribute__((address_space(1))) uint32_t*)(uintptr_t)(GSRC),         \
      (__attribute__((address_space(3))) uint32_t*)(uint32_t)(uintptr_t)(LDST),     \
      16, 0, 0)

// ---------------- kernel 0: W f32 -> bf16 ----------------
__global__ void wconv(const float* __restrict__ W, ushort* __restrict__ Wbf){
  int i = (blockIdx.x*256 + threadIdx.x)*4;   // 64 blocks
  float4 v = *reinterpret_cast<const float4*>(W + i);
  s16x4 o;
  o[0] = (short)f2bf(v.x); o[1] = (short)f2bf(v.y);
  o[2] = (short)f2bf(v.z); o[3] = (short)f2bf(v.w);
  *reinterpret_cast<s16x4*>(Wbf + i) = o;
}

// ---------------- kernel 1: fused GEMM + bilinear reduce ----------------
// score[m] = attn[m] * sum_e dis[m,e] * sum_k W[e,k] * drug[m,k]
// 8 waves: wave w -> e-slice s=w&3 (64 cols), k-half h=w>>2.
// LDS ring: 4 buffers of full f32 rows [16][512], chunk-XOR swizzle (chunk ^ (row&7)),
// source pre-swizzled for linear gload_lds dest (both-sides involution).
// Pipeline: counted vmcnt (never 0 in steady state), raw s_barrier, epilogue lagged 1 tile.
__global__ __launch_bounds__(512, 2)
void score_kernel(const float* __restrict__ emb, const float* __restrict__ attn,
                  const ushort* __restrict__ Wbf, float* __restrict__ scores){
  __shared__ float Lbuf[4][BM*FF];     // 4 x 32 KB ring
  __shared__ float red[2][8][BM];      // 1 KB, ping-pong by t&1
  __shared__ float attn_l[TPB*BM];     // 4 KB

  const int tid  = threadIdx.x;
  const int w    = tid >> 6;        // wave 0..7
  const int lane = tid & 63;
  const int g    = lane >> 4;
  const int c    = lane & 15;
  const int s    = w & 3;           // e-slice
  const int h    = w >> 2;          // k-half

  // attn for this block's 1024 rows -> LDS (synced by first barrier)
  attn_l[tid]       = attn[blockIdx.x*(TPB*BM) + tid];
  attn_l[tid + 512] = attn[blockIdx.x*(TPB*BM) + 512 + tid];

  // W B-fragments: B[k][e] = W[e][k]; e = s*64+eb*16+c, k = h*128+kb*32+g*8..+8  (64 VGPR)
  bf16x8 Wf[4][4];
#pragma unroll
  for (int eb = 0; eb < 4; ++eb)
#pragma unroll
    for (int kb = 0; kb < 4; ++kb){
      int e = s*64 + eb*16 + c;
      int k = h*128 + kb*32 + g*8;
      Wf[eb][kb] = *reinterpret_cast<const bf16x8*>(Wbf + e*DD + k);
    }

  // staging source offsets: issue i covers LDS 1KB region idx=w*4+i -> row r=idx>>1,
  // half hf=idx&1; lane fetches global chunk (lane ^ (r&7)) of that half.
  int offs[4];
#pragma unroll
  for (int i = 0; i < 4; ++i){
    int idx = w*4 + i;
    int r = idx >> 1, hf = idx & 1;
    offs[i] = r*FF + hf*256 + ((lane ^ (r & 7)) << 2);
  }
  const float* tbase = emb + (size_t)blockIdx.x * TPB * (BM*FF);

  // prologue: stage tiles 0,1,2 into ring slots 0,1,2
#pragma unroll
  for (int tt = 0; tt < 3; ++tt){
    const float* nb = tbase + (size_t)tt * (BM*FF);
#pragma unroll
    for (int i = 0; i < 4; ++i)
      GL2LDS(nb + offs[i], &Lbuf[tt][(w*4 + i)*256]);
  }

  for (int t = 0; t < TPB; ++t){
    // counted wait: own loads for tile t done; tiles t+1,t+2 stay in flight
    if (t + 2 < TPB)      asm volatile("s_waitcnt vmcnt(8) lgkmcnt(0)" ::: "memory");
    else if (t + 1 < TPB) asm volatile("s_waitcnt vmcnt(4) lgkmcnt(0)" ::: "memory");
    else                  asm volatile("s_waitcnt vmcnt(0) lgkmcnt(0)" ::: "memory");
    __builtin_amdgcn_s_barrier();            // all waves' tile-t loads landed
    __builtin_amdgcn_sched_barrier(0);

    // issue tile t+3 into ring slot (t+3)&3 (its last readers finished pre-barrier)
    if (t + 3 < TPB){
      const float* nb = tbase + (size_t)(t+3) * (BM*FF);
#pragma unroll
      for (int i = 0; i < 4; ++i)
        GL2LDS(nb + offs[i], &Lbuf[(t+3) & 3][(w*4 + i)*256]);
    }

    // epilogue for tile t-1 (red[(t-1)&1] made visible by this iteration's barrier)
    if (t > 0 && tid < BM){
      const int tp = t - 1;
      float sum = red[tp&1][0][tid] + red[tp&1][1][tid] + red[tp&1][2][tid] + red[tp&1][3][tid]
                + red[tp&1][4][tid] + red[tp&1][5][tid] + red[tp&1][6][tid] + red[tp&1][7][tid];
      int row = (blockIdx.x*TPB + tp)*BM + tid;
      scores[row] = attn_l[tp*BM + tid] * sum;
    }

    // ---- compute tile t from ring slot t&3 ----
    const f32x4* Lv = (const f32x4*)&Lbuf[t & 3][0];
    const int rb = c*128;             // row base in float4 units (row = c)
    const int x  = c & 7;
    bf16x8 af[4];
#pragma unroll
    for (int kb = 0; kb < 4; ++kb){   // drug chunks, swizzled lookup, cvt to bf16
      int ch0 = h*32 + kb*8 + g*2;
      f32x4 q0 = Lv[rb + ((ch0    ) ^ x)];
      f32x4 q1 = Lv[rb + ((ch0 + 1) ^ x)];
      af[kb] = cvt8(q0, q1);
    }
    float rs0=0.f, rs1=0.f, rs2=0.f, rs3=0.f;
#pragma unroll
    for (int eb = 0; eb < 4; ++eb){
      f32x4 acc = {0.f, 0.f, 0.f, 0.f};
#pragma unroll
      for (int kb = 0; kb < 4; ++kb)
        acc = __builtin_amdgcn_mfma_f32_16x16x32_bf16(af[kb], Wf[eb][kb], acc, 0, 0, 0);
      // C[g*4+j][s*64+eb*16+c] in acc[j]; dis read from swizzled f32 LDS (2-way max, free)
      const int sb = 64 + s*16 + eb*4 + (c >> 2);
      const int e3 = c & 3;
#pragma unroll
      for (int j = 0; j < 4; ++j){
        const int row = g*4 + j;
        const int fi  = row*FF + ((sb ^ (row & 7)) << 2) + e3;
        float d = Lbuf[t & 3][fi];
        if      (j == 0) rs0 += acc[0]*d;
        else if (j == 1) rs1 += acc[1]*d;
        else if (j == 2) rs2 += acc[2]*d;
        else             rs3 += acc[3]*d;
      }
    }
    rs0 += __shfl_xor(rs0,1); rs0 += __shfl_xor(rs0,2); rs0 += __shfl_xor(rs0,4); rs0 += __shfl_xor(rs0,8);
    rs1 += __shfl_xor(rs1,1); rs1 += __shfl_xor(rs1,2); rs1 += __shfl_xor(rs1,4); rs1 += __shfl_xor(rs1,8);
    rs2 += __shfl_xor(rs2,1); rs2 += __shfl_xor(rs2,2); rs2 += __shfl_xor(rs2,4); rs2 += __shfl_xor(rs2,8);
    rs3 += __shfl_xor(rs3,1); rs3 += __shfl_xor(rs3,2); rs3 += __shfl_xor(rs3,4); rs3 += __shfl_xor(rs3,8);
    if (c == 0){
      red[t&1][w][g*4 + 0] = rs0;
      red[t&1][w][g*4 + 1] = rs1;
      red[t&1][w][g*4 + 2] = rs2;
      red[t&1][w][g*4 + 3] = rs3;
    }
  }

  // final epilogue for tile TPB-1
  asm volatile("s_waitcnt lgkmcnt(0)" ::: "memory");
  __builtin_amdgcn_s_barrier();
  if (tid < BM){
    const int tp = TPB - 1;
    float sum = red[tp&1][0][tid] + red[tp&1][1][tid] + red[tp&1][2][tid] + red[tp&1][3][tid]
              + red[tp&1][4][tid] + red[tp&1][5][tid] + red[tp&1][6][tid] + red[tp&1][7][tid];
    int row = (blockIdx.x*TPB + tp)*BM + tid;
    scores[row] = attn_l[tp*BM + tid] * sum;
  }
}

// ---------------- kernel 2: per-batch top-K mean ----------------
__global__ void topk_kernel(const float* __restrict__ scores, float* __restrict__ out){
  const int b = blockIdx.x;
  const int lane = threadIdx.x;   // 64 threads
  float v0,v1,v2,v3,v4,v5,v6,v7;
  const float* sc = scores + b*NN;
  v0=sc[lane]; v1=sc[64+lane]; v2=sc[128+lane]; v3=sc[192+lane];
  v4=sc[256+lane]; v5=sc[320+lane]; v6=sc[384+lane]; v7=sc[448+lane];
  float total = 0.f;
  for (int it = 0; it < KTOP; ++it){
    float m = v0; int mj = 0;
    if (v1>m){m=v1;mj=1;} if (v2>m){m=v2;mj=2;} if (v3>m){m=v3;mj=3;}
    if (v4>m){m=v4;mj=4;} if (v5>m){m=v5;mj=5;} if (v6>m){m=v6;mj=6;}
    if (v7>m){m=v7;mj=7;}
    float bm = m; int bl = lane;
#pragma unroll
    for (int off = 32; off; off >>= 1){
      float om = __shfl_xor(bm, off);
      int   ol = __shfl_xor(bl, off);
      if (om > bm || (om == bm && ol < bl)){ bm = om; bl = ol; }
    }
    total += bm;
    if (lane == bl){
      if (mj==0) v0=-3.0e38f; else if (mj==1) v1=-3.0e38f;
      else if (mj==2) v2=-3.0e38f; else if (mj==3) v3=-3.0e38f;
      else if (mj==4) v4=-3.0e38f; else if (mj==5) v5=-3.0e38f;
      else if (mj==6) v6=-3.0e38f; else v7=-3.0e38f;
    }
  }
  if (lane == 0) out[b] = total * (1.0f / KTOP);
}

extern "C" void kernel_launch(void* const* d_in, const int* in_sizes, int n_in,
                              void* d_out, int out_size, void* d_ws, size_t ws_size,
                              hipStream_t stream){
  const float* emb  = (const float*)d_in[0];   // (B,N,F) f32
  const float* attn = (const float*)d_in[1];   // (B,N,1) f32
  const float* W    = (const float*)d_in[2];   // (D,D) f32
  float* out = (float*)d_out;                  // (B,1) f32

  ushort* Wbf    = (ushort*)d_ws;                                 // 128 KB
  float*  scores = (float*)((char*)d_ws + DD*DD*sizeof(ushort));  // 1 MB

  wconv<<<64, 256, 0, stream>>>(W, Wbf);
  score_kernel<<<GRID, 512, 0, stream>>>(emb, attn, Wbf, scores);
  topk_kernel<<<BB, 64, 0, stream>>>(scores, out);
}